// Round 1
// 114.170 us; speedup vs baseline: 1.0135x; 1.0135x over previous
//
#include <hip/hip_runtime.h>

// BatchIndependentLoss: SupCon-style loss, B=2048, V=2, D=256, N=4096.
// loss = -mean_i( lp_i - (W_i - e^{lp}*lp) / u_new[i%B] )
// Structure: barrier-free symmetric GEMM (one wave = one 64x64 upper-tri
// tile, 2080 tiles, frag-major 2 MB bf16 operand in L2) + fused row/col
// stats + tiny finalize dispatch.
// R9: factored-exp epilogue + occupancy attack.
//  (a) single-exp domain: accumulate f = exp2(d*C1), S1 += f, S2 += f*(d*C1)
//      for BOTH row and col views (d*C1 is shared; the per-row shift msd is
//      linear and applied in finalize: E = 2^m*S1, W = 2^m*(S2 + m*S1)).
//      Halves exp2 count (33.5M -> 16.8M), chain 8 ops/2 trans -> 6 ops/1.
//      gemm no longer reads msd at all; msd recovered from diagonal tiles
//      (Draw = d_ii*C1 = sd*C1), so prep's self-dot pass is deleted.
//  (b) depth-1 double buffer (frag regs 96 -> 64) + 32-bit offsets +
//      __launch_bounds__(64,3): VGPR cap 168 -> 3 waves/SIMD (was 2).
//      Latency-bound regime => +50% wave overlap beats the lost prefetch.
//  (c) s_setprio(1) around MFMA clusters (independent 1-wave blocks =
//      phase-diverse structure where setprio measured +4-7%).
//
// CmF layout: shorts, index = ((band*8 + k)*4 + rt)*512 + (l15*4+quad)*8 + j
// Fragment load for (band, k, rt): wave reads one contiguous 1 KB chunk.

#define BSZ   2048
#define NROW  4096
#define DDIM  256
#define NB64  64                       // 4096/64 bands
#define NT2   (NB64 * (NB64 + 1) / 2)  // 2080 upper-triangle 64x64 tiles
#define C1    (1.4426950408889634f / 0.07f)   // log2(e)/TEMPERATURE
#define LN2   0.6931471805599453f

typedef __attribute__((ext_vector_type(8))) __bf16 bf16x8;
typedef __attribute__((ext_vector_type(4))) float f32x4;

__device__ __forceinline__ short f2bs(float x) {
    __bf16 b = (__bf16)x;
    return __builtin_bit_cast(short, b);
}

// contrast row i = v*B + b  ->  features row b*V + v  (fp32, 256 elems)
__device__ __forceinline__ const float* crow_ptr(const float* feats, int i) {
    return feats + (((i & (BSZ - 1)) * 2 + (i >> 11)) << 8);
}

// ---------------- prep: frag-major bf16 pack, zero S1/S2 -------------------
__global__ __launch_bounds__(256) void prep_kernel(const float* __restrict__ feats,
        float* __restrict__ Szero, short* __restrict__ CmF) {
    int gid = blockIdx.x * 256 + threadIdx.x;    // 0..262143
    if (gid < 2 * NROW) Szero[gid] = 0.0f;       // zero S1 and S2

    int quad = gid & 3;
    int l15  = (gid >> 2) & 15;
    int rt   = (gid >> 6) & 3;
    int k    = (gid >> 8) & 7;
    int b    = gid >> 12;
    int srow = (b << 6) + (rt << 4) + l15;
    int kel  = (k << 5) + (quad << 3);
    const float4* fp = (const float4*)(crow_ptr(feats, srow) + kel);
    float4 v0 = fp[0], v1 = fp[1];
    short h[8] = { f2bs(v0.x), f2bs(v0.y), f2bs(v0.z), f2bs(v0.w),
                   f2bs(v1.x), f2bs(v1.y), f2bs(v1.z), f2bs(v1.w) };
    *(int4*)(CmF + gid * 8) = *(int4*)h;
}

// ---------------- barrier-free symmetric GEMM + stats ----------------------
// One 64-thread block == one wave == one 64x64 tile. Depth-1 prefetch,
// 3 waves/SIMD. Unshifted exp2 domain: t0 = d*C1; f = exp2(t0);
// S1 += f; S2 += f*t0  (per-row 2^msd shift applied in finalize).
__global__ __launch_bounds__(64, 3) void gemm_sym(const short* __restrict__ CmF,
        float* __restrict__ S1, float* __restrict__ S2,
        float* __restrict__ Praw, float* __restrict__ Draw) {
    int lane = threadIdx.x;          // 0..63
    int quad = lane >> 4;
    int l15  = lane & 15;

    // triangle decode t -> (p,q), p>=q
    int t = blockIdx.x;
    int p = (int)((sqrtf(8.0f * (float)t + 1.0f) - 1.0f) * 0.5f);
    while ((p + 1) * (p + 2) / 2 <= t) ++p;
    while (p * (p + 1) / 2 > t) --p;
    int q = t - p * (p + 1) / 2;
    int rowBase = q << 6;            // row band (64)
    int colBase = p << 6;            // col band, >= row band
    bool offdiag = (p != q);

    // 32-bit offsets off the uniform CmF base (saddr + voffset form)
    int laneOff = ((l15 << 2) + quad) * 8;
    int aO = q * 16384 + laneOff;
    int bO = p * 16384 + laneOff;

    f32x4 acc[4][4];
    #pragma unroll
    for (int a = 0; a < 4; ++a)
        #pragma unroll
        for (int c = 0; c < 4; ++c) acc[a][c] = (f32x4){0.f, 0.f, 0.f, 0.f};

    // depth-1 software pipeline: 2 rotating fragment buffers
    bf16x8 aF[2][4], bF[2][4];
    #pragma unroll
    for (int rt = 0; rt < 4; ++rt) {
        aF[0][rt] = *(const bf16x8*)(CmF + aO + rt * 512);
        bF[0][rt] = *(const bf16x8*)(CmF + bO + rt * 512);
    }

    #pragma unroll
    for (int k = 0; k < 8; ++k) {
        int cur = k & 1;
        int nxt = cur ^ 1;
        if (k < 7) {                 // issue loads for step k+1
            #pragma unroll
            for (int rt = 0; rt < 4; ++rt) {
                aF[nxt][rt] = *(const bf16x8*)(CmF + aO + ((k + 1) * 4 + rt) * 512);
                bF[nxt][rt] = *(const bf16x8*)(CmF + bO + ((k + 1) * 4 + rt) * 512);
            }
        }
        __builtin_amdgcn_s_setprio(1);
        #pragma unroll
        for (int rt = 0; rt < 4; ++rt)
            #pragma unroll
            for (int ct = 0; ct < 4; ++ct)
                acc[rt][ct] = __builtin_amdgcn_mfma_f32_16x16x32_bf16(
                    aF[cur][rt], bF[cur][ct], acc[rt][ct], 0, 0, 0);
        __builtin_amdgcn_s_setprio(0);
    }

    // ---- epilogue: C/D layout col = lane&15, row = quad*4 + reg  [m89/m91]
    // Unshifted domain: one exp2 per element, feeds BOTH row and col sums.
    float S1r[4][4] = {}, S2r[4][4] = {};
    float S1c[4] = {}, S2c[4] = {};
    #pragma unroll
    for (int rt = 0; rt < 4; ++rt) {
        #pragma unroll
        for (int ct = 0; ct < 4; ++ct) {
            #pragma unroll
            for (int r = 0; r < 4; ++r) {
                float d  = acc[rt][ct][r];
                float t0 = d * C1;
                float f  = __builtin_exp2f(t0);
                S1r[rt][r] += f;
                S2r[rt][r] = __builtin_fmaf(f, t0, S2r[rt][r]);
                if (offdiag) {
                    S1c[ct] += f;
                    S2c[ct] = __builtin_fmaf(f, t0, S2c[ct]);
                }
            }
        }
    }

    // ---- Praw: only tiles with p == q^32 contain positives (j = i^2048)
    if (p == (q ^ 32)) {
        // positive at ct==rt, lane with l15 == (quad<<2)+r; value symmetric
        if (quad == (l15 >> 2)) {
            int r = l15 & 3;
            #pragma unroll
            for (int rt = 0; rt < 4; ++rt) {
                float t0 = acc[rt][rt][r] * C1;
                Praw[rowBase + rt * 16 + l15] = t0;
                Praw[colBase + rt * 16 + l15] = t0;
            }
        }
    }
    // ---- Draw: diagonal tiles hold the self-dot (msd = -Draw in finalize)
    if (!offdiag) {
        if (quad == (l15 >> 2)) {
            int r = l15 & 3;
            #pragma unroll
            for (int rt = 0; rt < 4; ++rt)
                Draw[rowBase + rt * 16 + l15] = acc[rt][rt][r] * C1;
        }
    }

    // row-path: reduce over 16 l15 lanes per row, 1-lane atomic per row
    #pragma unroll
    for (int rt = 0; rt < 4; ++rt) {
        #pragma unroll
        for (int r = 0; r < 4; ++r) {
            float e = S1r[rt][r], w = S2r[rt][r];
            #pragma unroll
            for (int off = 1; off < 16; off <<= 1) {
                e += __shfl_xor(e, off, 64);
                w += __shfl_xor(w, off, 64);
            }
            if (l15 == 0) {
                int grow = rowBase + rt * 16 + (quad << 2) + r;
                atomicAdd(&S1[grow], e);
                atomicAdd(&S2[grow], w);
            }
        }
    }
    // col-path: reduce over 4 quads per col, 16-lane atomic
    if (offdiag) {
        #pragma unroll
        for (int ct = 0; ct < 4; ++ct) {
            float e = S1c[ct], w = S2c[ct];
            e += __shfl_xor(e, 16, 64);  w += __shfl_xor(w, 16, 64);
            e += __shfl_xor(e, 32, 64);  w += __shfl_xor(w, 32, 64);
            if (quad == 0) {
                int gcol = colBase + ct * 16 + l15;
                atomicAdd(&S1[gcol], e);
                atomicAdd(&S2[gcol], w);
            }
        }
    }
}

// ---------------- finalize: per-row shift, u_new, scalar reduction ---------
// m = -Draw[i]; E = 2^m*S1; W = 2^m*(S2 + m*S1); tp = Praw + m.
__global__ __launch_bounds__(1024) void finalize_kernel(const int* __restrict__ index,
        const float* __restrict__ u, const float* __restrict__ S1,
        const float* __restrict__ S2, const float* __restrict__ Praw,
        const float* __restrict__ Draw, float* __restrict__ out) {
    __shared__ float unew[BSZ];
    __shared__ float partial[16];
    int tid = threadIdx.x;
    for (int b = tid; b < BSZ; b += 1024) {
        float m  = -Draw[b];
        float tp = Praw[b] + m;
        float E  = __builtin_exp2f(m) * S1[b];
        unew[b] = 0.1f * u[index[b]] + 0.9f * (E - __builtin_exp2f(tp));
    }
    __syncthreads();
    float local = 0.0f;
    for (int i = tid; i < NROW; i += 1024) {
        float m   = -Draw[i];
        float tp  = Praw[i] + m;
        float etp = __builtin_exp2f(tp);
        float W   = __builtin_exp2f(m) * __builtin_fmaf(m, S1[i], S2[i]);
        local += tp - (W - etp * tp) / unew[i & (BSZ - 1)];
    }
    #pragma unroll
    for (int off = 32; off; off >>= 1) local += __shfl_xor(local, off, 64);
    if ((tid & 63) == 0) partial[tid >> 6] = local;
    __syncthreads();
    if (tid == 0) {
        float s = 0.0f;
        #pragma unroll
        for (int w = 0; w < 16; ++w) s += partial[w];
        out[0] = -LN2 * s / (float)NROW;   // exp2-domain -> nat-log domain
    }
}

extern "C" void kernel_launch(void* const* d_in, const int* in_sizes, int n_in,
                              void* d_out, int out_size, void* d_ws, size_t ws_size,
                              hipStream_t stream) {
    const int*   index = (const int*)d_in[0];
    const float* feats = (const float*)d_in[1];
    const float* u     = (const float*)d_in[2];
    float* out = (float*)d_out;

    // ws: [S1|S2|Praw|Draw] (4x4096 f32 = 64 KB) | ... | CmF @128KB (2 MB)
    float* S1   = (float*)d_ws;
    float* S2   = S1 + NROW;
    float* Praw = S2 + NROW;
    float* Draw = Praw + NROW;
    short* CmF  = (short*)((char*)d_ws + 131072);

    prep_kernel<<<1024, 256, 0, stream>>>(feats, S1, CmF);
    gemm_sym<<<NT2, 64, 0, stream>>>(CmF, S1, S2, Praw, Draw);
    finalize_kernel<<<1, 1024, 0, stream>>>(index, u, S1, S2, Praw, Draw, out);
}